// Round 1
// baseline (2254.238 us; speedup 1.0000x reference)
//
#include <hip/hip_runtime.h>
#include <hip/hip_bf16.h>

// ---------------------------------------------------------------------------
// GNN: 3x GraphConv(mean, edge-weighted) on N=100k nodes, E=1.6M edges, D=H=128
// Strategy:
//   1. Build CSR by dst once per call: histogram -> exclusive scan -> scatter.
//   2. deg_inv[i] = 1/deg (f32), fused into aggregation.
//   3. aggregate: one wave64 per node, float2 per lane (128 cols), no atomics.
//   4. fused GEMM: out = relu(agg@W_rel + b + in@W_root), both W in LDS (128KB).
// All f32 to match reference numerics closely.
// ---------------------------------------------------------------------------

#define DIM 128

__global__ void hist_kernel(const int* __restrict__ dst, int* __restrict__ counts, int E) {
    int e = blockIdx.x * blockDim.x + threadIdx.x;
    if (e < E) atomicAdd(&counts[dst[e]], 1);
}

__global__ __launch_bounds__(1024) void scan_excl(const int* __restrict__ counts,
                                                  int* __restrict__ offs, int n, int total) {
    __shared__ int wsum[16];
    __shared__ int carry_s;
    int lane = threadIdx.x & 63;
    int wid  = threadIdx.x >> 6;
    if (threadIdx.x == 0) carry_s = 0;
    __syncthreads();
    int nChunks = (n + 1023) >> 10;
    for (int c0 = 0; c0 < nChunks; ++c0) {
        int i = (c0 << 10) + (int)threadIdx.x;
        int v = (i < n) ? counts[i] : 0;
        int val = v;
        #pragma unroll
        for (int off = 1; off < 64; off <<= 1) {
            int t = __shfl_up(val, off);
            if (lane >= off) val += t;
        }
        if (lane == 63) wsum[wid] = val;
        __syncthreads();
        if (wid == 0) {
            int s = (lane < 16) ? wsum[lane] : 0;
            #pragma unroll
            for (int off = 1; off < 16; off <<= 1) {
                int t = __shfl_up(s, off);
                if (lane >= off) s += t;
            }
            if (lane < 16) wsum[lane] = s;
        }
        __syncthreads();
        int incl = val + ((wid > 0) ? wsum[wid - 1] : 0);
        int carry = carry_s;
        if (i < n) offs[i] = carry + incl - v;
        __syncthreads();
        if (threadIdx.x == 1023) carry_s = carry + incl;
        __syncthreads();
    }
    if (threadIdx.x == 0) offs[n] = total;
}

__global__ void deginv_kernel(const int* __restrict__ counts, float* __restrict__ deg_inv, int n) {
    int i = blockIdx.x * blockDim.x + threadIdx.x;
    if (i < n) deg_inv[i] = (counts[i] > 0) ? (1.0f / (float)counts[i]) : 0.0f;
}

__global__ void scatter_kernel(const int* __restrict__ edge_index,  // [2,E]: src then dst
                               const float* __restrict__ edge_attr,
                               const int* __restrict__ offs,
                               int* __restrict__ cursor,            // zeroed counts reused
                               int* __restrict__ srcs, float* __restrict__ wts, int E) {
    int e = blockIdx.x * blockDim.x + threadIdx.x;
    if (e >= E) return;
    int s = edge_index[e];
    int d = edge_index[E + e];
    int pos = offs[d] + atomicAdd(&cursor[d], 1);
    srcs[pos] = s;
    wts[pos]  = edge_attr[e];
}

// one wave64 per node; lane holds cols {2*lane, 2*lane+1}
__global__ __launch_bounds__(256) void aggregate_kernel(const float* __restrict__ feat,
                                                        const int* __restrict__ srcs,
                                                        const float* __restrict__ wts,
                                                        const int* __restrict__ offs,
                                                        const float* __restrict__ deg_inv,
                                                        float* __restrict__ agg, int n) {
    int node = blockIdx.x * 4 + (threadIdx.x >> 6);
    if (node >= n) return;
    int lane = threadIdx.x & 63;
    int beg = offs[node], end = offs[node + 1];
    float ax = 0.f, ay = 0.f;
    const int c = lane * 2;
    for (int e = beg; e < end; ++e) {
        int s = srcs[e];
        float wt = wts[e];
        float2 v = *reinterpret_cast<const float2*>(&feat[(size_t)s * DIM + c]);
        ax += v.x * wt;
        ay += v.y * wt;
    }
    float di = deg_inv[node];
    float2 r = make_float2(ax * di, ay * di);
    *reinterpret_cast<float2*>(&agg[(size_t)node * DIM + c]) = r;
}

// out = relu(agg @ Wrel + b + in @ Wroot); both W staged in LDS (128KB -> 1 blk/CU)
__global__ __launch_bounds__(256, 1) void gemm_fused(const float* __restrict__ in,
                                                     const float* __restrict__ agg,
                                                     const float* __restrict__ Wrel,
                                                     const float* __restrict__ Wroot,
                                                     const float* __restrict__ bias,
                                                     float* __restrict__ out, int n) {
    __shared__ float sW[2][DIM * DIM];   // 128KB
    __shared__ float sA[2][4][DIM];      // 4KB: [agg|in] rows for 4 nodes
    int col = threadIdx.x & 127;
    int g   = threadIdx.x >> 7;          // 0..1
    for (int i = threadIdx.x; i < DIM * DIM; i += 256) {
        sW[0][i] = Wrel[i];
        sW[1][i] = Wroot[i];
    }
    float bcol = bias[col];
    __syncthreads();
    for (int base = blockIdx.x * 4; base < n; base += gridDim.x * 4) {
        for (int t = threadIdx.x; t < 512; t += 256) {
            int r = t >> 7, c = t & 127;
            int node = base + r;
            float va = 0.f, vi = 0.f;
            if (node < n) {
                va = agg[(size_t)node * DIM + c];
                vi = in[(size_t)node * DIM + c];
            }
            sA[0][r][c] = va;
            sA[1][r][c] = vi;
        }
        __syncthreads();
        int n0 = g * 2;
        float acc0 = bcol, acc1 = bcol;
        #pragma unroll 8
        for (int k = 0; k < DIM; ++k) {
            float wr = sW[0][k * DIM + col];
            float wo = sW[1][k * DIM + col];
            acc0 += sA[0][n0][k] * wr + sA[1][n0][k] * wo;
            acc1 += sA[0][n0 + 1][k] * wr + sA[1][n0 + 1][k] * wo;
        }
        int node0 = base + n0;
        if (node0 < n)     out[(size_t)node0 * DIM + col]       = fmaxf(acc0, 0.f);
        if (node0 + 1 < n) out[(size_t)(node0 + 1) * DIM + col] = fmaxf(acc1, 0.f);
        __syncthreads();
    }
}

extern "C" void kernel_launch(void* const* d_in, const int* in_sizes, int n_in,
                              void* d_out, int out_size, void* d_ws, size_t ws_size,
                              hipStream_t stream) {
    const float* x          = (const float*)d_in[0];
    const int*   edge_index = (const int*)d_in[1];
    const float* edge_attr  = (const float*)d_in[2];
    const float* Wrel1 = (const float*)d_in[3];
    const float* b1    = (const float*)d_in[4];
    const float* Wroot1= (const float*)d_in[5];
    const float* Wrel2 = (const float*)d_in[6];
    const float* b2    = (const float*)d_in[7];
    const float* Wroot2= (const float*)d_in[8];
    const float* Wrel3 = (const float*)d_in[9];
    const float* b3    = (const float*)d_in[10];
    const float* Wroot3= (const float*)d_in[11];

    const int N = in_sizes[0] / DIM;
    const int E = in_sizes[2];

    // workspace carve-up (256B aligned)
    size_t off = 0;
    auto carve = [&](size_t bytes) -> char* {
        char* p = (char*)d_ws + off;
        off = (off + bytes + 255) & ~(size_t)255;
        return p;
    };
    int*   counts  = (int*)  carve((size_t)N * 4);
    int*   offs    = (int*)  carve((size_t)(N + 1) * 4);
    float* deg_inv = (float*)carve((size_t)N * 4);
    int*   srcs    = (int*)  carve((size_t)E * 4);
    float* wts     = (float*)carve((size_t)E * 4);
    float* agg     = (float*)carve((size_t)N * DIM * 4);
    float* h       = (float*)carve((size_t)N * DIM * 4);
    float* outp    = (float*)d_out;

    // 1. CSR build
    hipMemsetAsync(counts, 0, (size_t)N * 4, stream);
    hist_kernel<<<(E + 255) / 256, 256, 0, stream>>>(edge_index + E, counts, E);
    scan_excl<<<1, 1024, 0, stream>>>(counts, offs, N, E);
    deginv_kernel<<<(N + 255) / 256, 256, 0, stream>>>(counts, deg_inv, N);
    hipMemsetAsync(counts, 0, (size_t)N * 4, stream);
    scatter_kernel<<<(E + 255) / 256, 256, 0, stream>>>(edge_index, edge_attr, offs, counts,
                                                        srcs, wts, E);

    dim3 aggGrid((N + 3) / 4);
    dim3 gemmGrid(256);

    // Layer 1: x -> h
    aggregate_kernel<<<aggGrid, 256, 0, stream>>>(x, srcs, wts, offs, deg_inv, agg, N);
    gemm_fused<<<gemmGrid, 256, 0, stream>>>(x, agg, Wrel1, Wroot1, b1, h, N);
    // Layer 2: h -> d_out
    aggregate_kernel<<<aggGrid, 256, 0, stream>>>(h, srcs, wts, offs, deg_inv, agg, N);
    gemm_fused<<<gemmGrid, 256, 0, stream>>>(h, agg, Wrel2, Wroot2, b2, outp, N);
    // Layer 3: d_out -> d_out (in-place safe: rows staged to LDS before write)
    aggregate_kernel<<<aggGrid, 256, 0, stream>>>(outp, srcs, wts, offs, deg_inv, agg, N);
    gemm_fused<<<gemmGrid, 256, 0, stream>>>(outp, agg, Wrel3, Wroot3, b3, outp, N);
}

// Round 2
// 1141.163 us; speedup vs baseline: 1.9754x; 1.9754x over previous
//
#include <hip/hip_runtime.h>
#include <hip/hip_bf16.h>

// ---------------------------------------------------------------------------
// GNN: 3x GraphConv(mean, edge-weighted) on N=100k nodes, E=1.6M edges, D=H=128
//   1. CSR build: histogram -> wave-scan+atomic base (order-free) -> scatter.
//   2. aggregate: one wave64 per node, float2 per lane, no atomics.
//   3. register-tiled f32 GEMM: out = relu([agg|in] @ [Wrel;Wroot] + b)
//      BM=128, BN=128, BK=64, 256 thr, 8x8 acc/thread, VALU-bound by design.
// ---------------------------------------------------------------------------

#define DIM 128

__global__ void hist_kernel(const int* __restrict__ dst, int* __restrict__ counts, int E) {
    int e = blockIdx.x * blockDim.x + threadIdx.x;
    if (e < E) atomicAdd(&counts[dst[e]], 1);
}

// beg[i] = running base (order across nodes irrelevant for segment mean)
__global__ void assign_kernel(const int* __restrict__ counts, int* __restrict__ beg,
                              float* __restrict__ deg_inv, int* __restrict__ total, int n) {
    int i = blockIdx.x * blockDim.x + threadIdx.x;
    int lane = threadIdx.x & 63;
    int c = (i < n) ? counts[i] : 0;
    int s = c;
    #pragma unroll
    for (int off = 1; off < 64; off <<= 1) {
        int t = __shfl_up(s, off);
        if (lane >= off) s += t;
    }
    int wtot = __shfl(s, 63);
    int wbase = 0;
    if (lane == 63) wbase = atomicAdd(total, wtot);
    wbase = __shfl(wbase, 63);
    if (i < n) {
        beg[i] = wbase + s - c;
        deg_inv[i] = (c > 0) ? 1.0f / (float)c : 0.0f;
    }
}

__global__ void scatter_kernel(const int* __restrict__ edge_index,  // [2,E]
                               const float* __restrict__ edge_attr,
                               const int* __restrict__ beg,
                               int* __restrict__ cursor,
                               int* __restrict__ srcs, float* __restrict__ wts, int E) {
    int e = blockIdx.x * blockDim.x + threadIdx.x;
    if (e >= E) return;
    int s = edge_index[e];
    int d = edge_index[E + e];
    int pos = beg[d] + atomicAdd(&cursor[d], 1);
    srcs[pos] = s;
    wts[pos]  = edge_attr[e];
}

// one wave64 per node; lane holds cols {2*lane, 2*lane+1}
__global__ __launch_bounds__(256) void aggregate_kernel(const float* __restrict__ feat,
                                                        const int* __restrict__ srcs,
                                                        const float* __restrict__ wts,
                                                        const int* __restrict__ beg,
                                                        const int* __restrict__ counts,
                                                        const float* __restrict__ deg_inv,
                                                        float* __restrict__ agg, int n) {
    int node = blockIdx.x * 4 + (threadIdx.x >> 6);
    if (node >= n) return;
    int lane = threadIdx.x & 63;
    int b = beg[node];
    int end = b + counts[node];
    float ax = 0.f, ay = 0.f;
    const int c = lane * 2;
    for (int e = b; e < end; ++e) {
        int s = srcs[e];
        float wt = wts[e];
        float2 v = *reinterpret_cast<const float2*>(&feat[(size_t)s * DIM + c]);
        ax += v.x * wt;
        ay += v.y * wt;
    }
    float di = deg_inv[node];
    float2 r = make_float2(ax * di, ay * di);
    *reinterpret_cast<float2*>(&agg[(size_t)node * DIM + c]) = r;
}

// ---------------------------------------------------------------------------
// Register-tiled fused GEMM: out[M,128] = relu(agg@Wrel + in@Wroot + b)
// Viewed as C = A' @ W' with A' = [agg|in] (K=256), W' = [Wrel;Wroot].
// BM=128, BN=128, BK=64. 256 threads: tn=tid&15 (8 cols), tm=tid>>4 (8 rows).
// sA: [BK][132] transposed (stride 132 -> 16B-aligned, conflict-free b128).
// sW: [BK][128] half-split swizzle: logical n -> phys (n>>3)*4+((n>>2)&1)*64+(n&3)
//     so the wave's 16 ds_read_b128 cover 64 consecutive floats (2-way = free).
// ---------------------------------------------------------------------------
#define BM 128
#define BK 64
#define SA_STRIDE 132

__global__ __launch_bounds__(256, 2) void gemm_fused(const float* __restrict__ in,
                                                     const float* __restrict__ agg,
                                                     const float* __restrict__ Wrel,
                                                     const float* __restrict__ Wroot,
                                                     const float* __restrict__ bias,
                                                     float* __restrict__ out, int n) {
    __shared__ float sA[BK * SA_STRIDE];   // 33792 B
    __shared__ float sW[BK * DIM];         // 32768 B
    const int tid = threadIdx.x;
    const int tn = tid & 15;       // col group: cols tn*8 .. tn*8+7
    const int tm = tid >> 4;       // row group: rows tm*8 .. tm*8+7
    const int m0 = blockIdx.x * BM;

    float acc[8][8];
    #pragma unroll
    for (int i = 0; i < 8; ++i)
        #pragma unroll
        for (int j = 0; j < 8; ++j) acc[i][j] = 0.f;

    for (int chunk = 0; chunk < 4; ++chunk) {
        const float* Asrc = (chunk < 2) ? agg : in;
        const int kb = (chunk & 1) * 64;
        const float* Wsrc = ((chunk < 2) ? Wrel : Wroot) + kb * DIM;

        // stage A tile (transpose): 2048 float4, 8 per thread
        #pragma unroll
        for (int i = 0; i < 8; ++i) {
            int f = tid + i * 256;
            int m = f >> 4, c = f & 15;            // k = 4c..4c+3
            int node = m0 + m;
            float4 v = make_float4(0.f, 0.f, 0.f, 0.f);
            if (node < n) v = *reinterpret_cast<const float4*>(&Asrc[(size_t)node * DIM + kb + c * 4]);
            sA[(c * 4 + 0) * SA_STRIDE + m] = v.x;
            sA[(c * 4 + 1) * SA_STRIDE + m] = v.y;
            sA[(c * 4 + 2) * SA_STRIDE + m] = v.z;
            sA[(c * 4 + 3) * SA_STRIDE + m] = v.w;
        }
        // stage W tile (swizzled): 2048 float4, 8 per thread
        #pragma unroll
        for (int i = 0; i < 8; ++i) {
            int f = tid + i * 256;
            int k = f >> 5, c = f & 31;            // n = 4c..4c+3
            float4 v = *reinterpret_cast<const float4*>(&Wsrc[k * DIM + c * 4]);
            int phys = k * DIM + (c >> 1) * 4 + (c & 1) * 64;
            *reinterpret_cast<float4*>(&sW[phys]) = v;
        }
        __syncthreads();

        #pragma unroll 2
        for (int k = 0; k < BK; ++k) {
            float4 a0 = *reinterpret_cast<const float4*>(&sA[k * SA_STRIDE + tm * 8]);
            float4 a1 = *reinterpret_cast<const float4*>(&sA[k * SA_STRIDE + tm * 8 + 4]);
            float4 w0 = *reinterpret_cast<const float4*>(&sW[k * DIM + tn * 4]);       // n=tn*8..+3
            float4 w1 = *reinterpret_cast<const float4*>(&sW[k * DIM + tn * 4 + 64]);  // n=tn*8+4..+7
            float a[8] = {a0.x, a0.y, a0.z, a0.w, a1.x, a1.y, a1.z, a1.w};
            float w[8] = {w0.x, w0.y, w0.z, w0.w, w1.x, w1.y, w1.z, w1.w};
            #pragma unroll
            for (int i = 0; i < 8; ++i)
                #pragma unroll
                for (int j = 0; j < 8; ++j)
                    acc[i][j] = fmaf(a[i], w[j], acc[i][j]);
        }
        __syncthreads();
    }

    // epilogue: bias + relu + store
    float4 b0 = *reinterpret_cast<const float4*>(&bias[tn * 8]);
    float4 b1 = *reinterpret_cast<const float4*>(&bias[tn * 8 + 4]);
    float bb[8] = {b0.x, b0.y, b0.z, b0.w, b1.x, b1.y, b1.z, b1.w};
    #pragma unroll
    for (int i = 0; i < 8; ++i) {
        int node = m0 + tm * 8 + i;
        if (node < n) {
            float4 o0 = make_float4(fmaxf(acc[i][0] + bb[0], 0.f), fmaxf(acc[i][1] + bb[1], 0.f),
                                    fmaxf(acc[i][2] + bb[2], 0.f), fmaxf(acc[i][3] + bb[3], 0.f));
            float4 o1 = make_float4(fmaxf(acc[i][4] + bb[4], 0.f), fmaxf(acc[i][5] + bb[5], 0.f),
                                    fmaxf(acc[i][6] + bb[6], 0.f), fmaxf(acc[i][7] + bb[7], 0.f));
            *reinterpret_cast<float4*>(&out[(size_t)node * DIM + tn * 8])     = o0;
            *reinterpret_cast<float4*>(&out[(size_t)node * DIM + tn * 8 + 4]) = o1;
        }
    }
}

extern "C" void kernel_launch(void* const* d_in, const int* in_sizes, int n_in,
                              void* d_out, int out_size, void* d_ws, size_t ws_size,
                              hipStream_t stream) {
    const float* x          = (const float*)d_in[0];
    const int*   edge_index = (const int*)d_in[1];
    const float* edge_attr  = (const float*)d_in[2];
    const float* Wrel1 = (const float*)d_in[3];
    const float* b1    = (const float*)d_in[4];
    const float* Wroot1= (const float*)d_in[5];
    const float* Wrel2 = (const float*)d_in[6];
    const float* b2    = (const float*)d_in[7];
    const float* Wroot2= (const float*)d_in[8];
    const float* Wrel3 = (const float*)d_in[9];
    const float* b3    = (const float*)d_in[10];
    const float* Wroot3= (const float*)d_in[11];

    const int N = in_sizes[0] / DIM;
    const int E = in_sizes[2];

    size_t off = 0;
    auto carve = [&](size_t bytes) -> char* {
        char* p = (char*)d_ws + off;
        off = (off + bytes + 255) & ~(size_t)255;
        return p;
    };
    size_t zero_beg = 0;
    int*   counts  = (int*)  carve((size_t)N * 4);
    int*   cursor  = (int*)  carve((size_t)N * 4);
    int*   total   = (int*)  carve(256);
    size_t zero_end = off;
    int*   begb    = (int*)  carve((size_t)N * 4);
    float* deg_inv = (float*)carve((size_t)N * 4);
    int*   srcs    = (int*)  carve((size_t)E * 4);
    float* wts     = (float*)carve((size_t)E * 4);
    float* agg     = (float*)carve((size_t)N * DIM * 4);
    float* h       = (float*)carve((size_t)N * DIM * 4);
    float* outp    = (float*)d_out;
    (void)zero_beg; (void)ws_size; (void)n_in; (void)out_size;

    // 1. CSR build (zero counts+cursor+total in one memset)
    hipMemsetAsync(counts, 0, zero_end, stream);
    hist_kernel<<<(E + 255) / 256, 256, 0, stream>>>(edge_index + E, counts, E);
    assign_kernel<<<(N + 255) / 256, 256, 0, stream>>>(counts, begb, deg_inv, total, N);
    scatter_kernel<<<(E + 255) / 256, 256, 0, stream>>>(edge_index, edge_attr, begb, cursor,
                                                        srcs, wts, E);

    dim3 aggGrid((N + 3) / 4);
    dim3 gemmGrid((N + BM - 1) / BM);

    // Layer 1: x -> h
    aggregate_kernel<<<aggGrid, 256, 0, stream>>>(x, srcs, wts, begb, counts, deg_inv, agg, N);
    gemm_fused<<<gemmGrid, 256, 0, stream>>>(x, agg, Wrel1, Wroot1, b1, h, N);
    // Layer 2: h -> d_out
    aggregate_kernel<<<aggGrid, 256, 0, stream>>>(h, srcs, wts, begb, counts, deg_inv, agg, N);
    gemm_fused<<<gemmGrid, 256, 0, stream>>>(h, agg, Wrel2, Wroot2, b2, outp, N);
    // Layer 3: d_out -> d_out (block reads only its own rows before writing them)
    aggregate_kernel<<<aggGrid, 256, 0, stream>>>(outp, srcs, wts, begb, counts, deg_inv, agg, N);
    gemm_fused<<<gemmGrid, 256, 0, stream>>>(outp, agg, Wrel3, Wroot3, b3, outp, N);
}

// Round 3
// 971.699 us; speedup vs baseline: 2.3199x; 1.1744x over previous
//
#include <hip/hip_runtime.h>
#include <hip/hip_bf16.h>

// ---------------------------------------------------------------------------
// GNN: 3x GraphConv(mean, edge-weighted) on N=100k nodes, E=1.6M edges, D=H=128
//   1. CSR build: histogram -> wave-scan+atomic base (order-free) -> scatter.
//   2. aggregate: one wave64 per node, float2 per lane, edge loop unrolled x8
//      with scalarized srcs/wts loads for MLP (latency-bound fix).
//   3. register-tiled f32 GEMM: out = relu([agg|in] @ [Wrel;Wroot] + b)
//      BM=128, BN=128, BK=64, 256 thr, 8x8 acc/thread.
// ---------------------------------------------------------------------------

#define DIM 128

__global__ void hist_kernel(const int* __restrict__ dst, int* __restrict__ counts, int E) {
    int e = blockIdx.x * blockDim.x + threadIdx.x;
    if (e < E) atomicAdd(&counts[dst[e]], 1);
}

// beg[i] = running base (order across nodes irrelevant for segment mean)
__global__ void assign_kernel(const int* __restrict__ counts, int* __restrict__ beg,
                              float* __restrict__ deg_inv, int* __restrict__ total, int n) {
    int i = blockIdx.x * blockDim.x + threadIdx.x;
    int lane = threadIdx.x & 63;
    int c = (i < n) ? counts[i] : 0;
    int s = c;
    #pragma unroll
    for (int off = 1; off < 64; off <<= 1) {
        int t = __shfl_up(s, off);
        if (lane >= off) s += t;
    }
    int wtot = __shfl(s, 63);
    int wbase = 0;
    if (lane == 63) wbase = atomicAdd(total, wtot);
    wbase = __shfl(wbase, 63);
    if (i < n) {
        beg[i] = wbase + s - c;
        deg_inv[i] = (c > 0) ? 1.0f / (float)c : 0.0f;
    }
}

__global__ void scatter_kernel(const int* __restrict__ edge_index,  // [2,E]
                               const float* __restrict__ edge_attr,
                               const int* __restrict__ beg,
                               int* __restrict__ cursor,
                               int* __restrict__ srcs, float* __restrict__ wts, int E) {
    int e = blockIdx.x * blockDim.x + threadIdx.x;
    if (e >= E) return;
    int s = edge_index[e];
    int d = edge_index[E + e];
    int pos = beg[d] + atomicAdd(&cursor[d], 1);
    srcs[pos] = s;
    wts[pos]  = edge_attr[e];
}

// one wave64 per node; lane holds cols {2*lane, 2*lane+1}; edge loop unrolled
// x8 so 8 independent 512B row-gathers are in flight per wave (MLP).
__global__ __launch_bounds__(256) void aggregate_kernel(const float* __restrict__ feat,
                                                        const int* __restrict__ srcs,
                                                        const float* __restrict__ wts,
                                                        const int* __restrict__ beg,
                                                        const int* __restrict__ counts,
                                                        const float* __restrict__ deg_inv,
                                                        float* __restrict__ agg, int n) {
    int node = blockIdx.x * 4 + (threadIdx.x >> 6);
    if (node >= n) return;
    const int c = (threadIdx.x & 63) * 2;
    // wave-uniform: lets compiler scalarize srcs/wts loads (s_load)
    int b   = __builtin_amdgcn_readfirstlane(beg[node]);
    int cnt = __builtin_amdgcn_readfirstlane(counts[node]);
    float ax = 0.f, ay = 0.f;
    int e = 0;
    for (; e + 8 <= cnt; e += 8) {
        int   s[8];
        float w[8];
        #pragma unroll
        for (int u = 0; u < 8; ++u) { s[u] = srcs[b + e + u]; w[u] = wts[b + e + u]; }
        float2 v[8];
        #pragma unroll
        for (int u = 0; u < 8; ++u)
            v[u] = *reinterpret_cast<const float2*>(&feat[(size_t)s[u] * DIM + c]);
        #pragma unroll
        for (int u = 0; u < 8; ++u) { ax = fmaf(v[u].x, w[u], ax); ay = fmaf(v[u].y, w[u], ay); }
    }
    for (; e + 4 <= cnt; e += 4) {
        int   s[4];
        float w[4];
        #pragma unroll
        for (int u = 0; u < 4; ++u) { s[u] = srcs[b + e + u]; w[u] = wts[b + e + u]; }
        float2 v[4];
        #pragma unroll
        for (int u = 0; u < 4; ++u)
            v[u] = *reinterpret_cast<const float2*>(&feat[(size_t)s[u] * DIM + c]);
        #pragma unroll
        for (int u = 0; u < 4; ++u) { ax = fmaf(v[u].x, w[u], ax); ay = fmaf(v[u].y, w[u], ay); }
    }
    for (; e < cnt; ++e) {
        int s = srcs[b + e];
        float wt = wts[b + e];
        float2 v = *reinterpret_cast<const float2*>(&feat[(size_t)s * DIM + c]);
        ax = fmaf(v.x, wt, ax);
        ay = fmaf(v.y, wt, ay);
    }
    float di = deg_inv[node];
    float2 r = make_float2(ax * di, ay * di);
    *reinterpret_cast<float2*>(&agg[(size_t)node * DIM + c]) = r;
}

// ---------------------------------------------------------------------------
// Register-tiled fused GEMM: out[M,128] = relu(agg@Wrel + in@Wroot + b)
// Viewed as C = A' @ W' with A' = [agg|in] (K=256), W' = [Wrel;Wroot].
// BM=128, BN=128, BK=64. 256 threads: tn=tid&15 (8 cols), tm=tid>>4 (8 rows).
// sA: [BK][132] transposed (stride 132 -> 16B-aligned, conflict-free b128).
// sW: [BK][128] half-split swizzle: logical n -> phys (n>>3)*4+((n>>2)&1)*64+(n&3)
// ---------------------------------------------------------------------------
#define BM 128
#define BK 64
#define SA_STRIDE 132

__global__ __launch_bounds__(256, 2) void gemm_fused(const float* __restrict__ in,
                                                     const float* __restrict__ agg,
                                                     const float* __restrict__ Wrel,
                                                     const float* __restrict__ Wroot,
                                                     const float* __restrict__ bias,
                                                     float* __restrict__ out, int n) {
    __shared__ float sA[BK * SA_STRIDE];   // 33792 B
    __shared__ float sW[BK * DIM];         // 32768 B
    const int tid = threadIdx.x;
    const int tn = tid & 15;       // col group: cols tn*8 .. tn*8+7
    const int tm = tid >> 4;       // row group: rows tm*8 .. tm*8+7
    const int m0 = blockIdx.x * BM;

    float acc[8][8];
    #pragma unroll
    for (int i = 0; i < 8; ++i)
        #pragma unroll
        for (int j = 0; j < 8; ++j) acc[i][j] = 0.f;

    for (int chunk = 0; chunk < 4; ++chunk) {
        const float* Asrc = (chunk < 2) ? agg : in;
        const int kb = (chunk & 1) * 64;
        const float* Wsrc = ((chunk < 2) ? Wrel : Wroot) + kb * DIM;

        // stage A tile (transpose): 2048 float4, 8 per thread
        #pragma unroll
        for (int i = 0; i < 8; ++i) {
            int f = tid + i * 256;
            int m = f >> 4, c = f & 15;            // k = 4c..4c+3
            int node = m0 + m;
            float4 v = make_float4(0.f, 0.f, 0.f, 0.f);
            if (node < n) v = *reinterpret_cast<const float4*>(&Asrc[(size_t)node * DIM + kb + c * 4]);
            sA[(c * 4 + 0) * SA_STRIDE + m] = v.x;
            sA[(c * 4 + 1) * SA_STRIDE + m] = v.y;
            sA[(c * 4 + 2) * SA_STRIDE + m] = v.z;
            sA[(c * 4 + 3) * SA_STRIDE + m] = v.w;
        }
        // stage W tile (swizzled): 2048 float4, 8 per thread
        #pragma unroll
        for (int i = 0; i < 8; ++i) {
            int f = tid + i * 256;
            int k = f >> 5, c = f & 31;            // n = 4c..4c+3
            float4 v = *reinterpret_cast<const float4*>(&Wsrc[k * DIM + c * 4]);
            int phys = k * DIM + (c >> 1) * 4 + (c & 1) * 64;
            *reinterpret_cast<float4*>(&sW[phys]) = v;
        }
        __syncthreads();

        #pragma unroll 2
        for (int k = 0; k < BK; ++k) {
            float4 a0 = *reinterpret_cast<const float4*>(&sA[k * SA_STRIDE + tm * 8]);
            float4 a1 = *reinterpret_cast<const float4*>(&sA[k * SA_STRIDE + tm * 8 + 4]);
            float4 w0 = *reinterpret_cast<const float4*>(&sW[k * DIM + tn * 4]);       // n=tn*8..+3
            float4 w1 = *reinterpret_cast<const float4*>(&sW[k * DIM + tn * 4 + 64]);  // n=tn*8+4..+7
            float a[8] = {a0.x, a0.y, a0.z, a0.w, a1.x, a1.y, a1.z, a1.w};
            float w[8] = {w0.x, w0.y, w0.z, w0.w, w1.x, w1.y, w1.z, w1.w};
            #pragma unroll
            for (int i = 0; i < 8; ++i)
                #pragma unroll
                for (int j = 0; j < 8; ++j)
                    acc[i][j] = fmaf(a[i], w[j], acc[i][j]);
        }
        __syncthreads();
    }

    // epilogue: bias + relu + store
    float4 b0 = *reinterpret_cast<const float4*>(&bias[tn * 8]);
    float4 b1 = *reinterpret_cast<const float4*>(&bias[tn * 8 + 4]);
    float bb[8] = {b0.x, b0.y, b0.z, b0.w, b1.x, b1.y, b1.z, b1.w};
    #pragma unroll
    for (int i = 0; i < 8; ++i) {
        int node = m0 + tm * 8 + i;
        if (node < n) {
            float4 o0 = make_float4(fmaxf(acc[i][0] + bb[0], 0.f), fmaxf(acc[i][1] + bb[1], 0.f),
                                    fmaxf(acc[i][2] + bb[2], 0.f), fmaxf(acc[i][3] + bb[3], 0.f));
            float4 o1 = make_float4(fmaxf(acc[i][4] + bb[4], 0.f), fmaxf(acc[i][5] + bb[5], 0.f),
                                    fmaxf(acc[i][6] + bb[6], 0.f), fmaxf(acc[i][7] + bb[7], 0.f));
            *reinterpret_cast<float4*>(&out[(size_t)node * DIM + tn * 8])     = o0;
            *reinterpret_cast<float4*>(&out[(size_t)node * DIM + tn * 8 + 4]) = o1;
        }
    }
}

extern "C" void kernel_launch(void* const* d_in, const int* in_sizes, int n_in,
                              void* d_out, int out_size, void* d_ws, size_t ws_size,
                              hipStream_t stream) {
    const float* x          = (const float*)d_in[0];
    const int*   edge_index = (const int*)d_in[1];
    const float* edge_attr  = (const float*)d_in[2];
    const float* Wrel1 = (const float*)d_in[3];
    const float* b1    = (const float*)d_in[4];
    const float* Wroot1= (const float*)d_in[5];
    const float* Wrel2 = (const float*)d_in[6];
    const float* b2    = (const float*)d_in[7];
    const float* Wroot2= (const float*)d_in[8];
    const float* Wrel3 = (const float*)d_in[9];
    const float* b3    = (const float*)d_in[10];
    const float* Wroot3= (const float*)d_in[11];

    const int N = in_sizes[0] / DIM;
    const int E = in_sizes[2];

    size_t off = 0;
    auto carve = [&](size_t bytes) -> char* {
        char* p = (char*)d_ws + off;
        off = (off + bytes + 255) & ~(size_t)255;
        return p;
    };
    int*   counts  = (int*)  carve((size_t)N * 4);
    int*   cursor  = (int*)  carve((size_t)N * 4);
    int*   total   = (int*)  carve(256);
    size_t zero_end = off;
    int*   begb    = (int*)  carve((size_t)N * 4);
    float* deg_inv = (float*)carve((size_t)N * 4);
    int*   srcs    = (int*)  carve((size_t)E * 4);
    float* wts     = (float*)carve((size_t)E * 4);
    float* agg     = (float*)carve((size_t)N * DIM * 4);
    float* h       = (float*)carve((size_t)N * DIM * 4);
    float* outp    = (float*)d_out;
    (void)ws_size; (void)n_in; (void)out_size;

    // 1. CSR build (zero counts+cursor+total in one memset)
    hipMemsetAsync(counts, 0, zero_end, stream);
    hist_kernel<<<(E + 255) / 256, 256, 0, stream>>>(edge_index + E, counts, E);
    assign_kernel<<<(N + 255) / 256, 256, 0, stream>>>(counts, begb, deg_inv, total, N);
    scatter_kernel<<<(E + 255) / 256, 256, 0, stream>>>(edge_index, edge_attr, begb, cursor,
                                                        srcs, wts, E);

    dim3 aggGrid((N + 3) / 4);
    dim3 gemmGrid((N + BM - 1) / BM);

    // Layer 1: x -> h
    aggregate_kernel<<<aggGrid, 256, 0, stream>>>(x, srcs, wts, begb, counts, deg_inv, agg, N);
    gemm_fused<<<gemmGrid, 256, 0, stream>>>(x, agg, Wrel1, Wroot1, b1, h, N);
    // Layer 2: h -> d_out
    aggregate_kernel<<<aggGrid, 256, 0, stream>>>(h, srcs, wts, begb, counts, deg_inv, agg, N);
    gemm_fused<<<gemmGrid, 256, 0, stream>>>(h, agg, Wrel2, Wroot2, b2, outp, N);
    // Layer 3: d_out -> d_out (block reads only its own rows before writing them)
    aggregate_kernel<<<aggGrid, 256, 0, stream>>>(outp, srcs, wts, begb, counts, deg_inv, agg, N);
    gemm_fused<<<gemmGrid, 256, 0, stream>>>(outp, agg, Wrel3, Wroot3, b3, outp, N);
}

// Round 4
// 861.730 us; speedup vs baseline: 2.6159x; 1.1276x over previous
//
#include <hip/hip_runtime.h>
#include <hip/hip_bf16.h>

// ---------------------------------------------------------------------------
// GNN: 3x GraphConv(mean, edge-weighted), N=100k, E=1.6M, D=H=128.
//   CSR build: histogram -> wave-scan+atomic base -> packed (src,wt) scatter.
//   aggregate: wave per node, gathers bf16 hi/lo feature rows (h+l == f32 to
//              2^-18), writes agg as bf16 hi/lo.
//   GEMM: bf16 MFMA 16x16x32, 3-term split (Ah*Wh + Ah*Wl + Al*Wh), 128x128
//         tile, 4 waves x 4x4 frags, double-buffered LDS via global_load_lds,
//         granule-transposed LDS layout (conflict-free ds_read_b128).
// ---------------------------------------------------------------------------

#define DIM 128
typedef unsigned short ushort_t;
typedef unsigned int uint_t;
typedef __attribute__((ext_vector_type(8))) short bf16x8;
typedef __attribute__((ext_vector_type(4))) float f32x4;

__device__ __forceinline__ ushort_t f2bf(float x) {           // RNE bf16 bits
    uint_t u = __float_as_uint(x);
    u = (u + 0x7fff + ((u >> 16) & 1)) >> 16;
    return (ushort_t)u;
}
__device__ __forceinline__ float bf2f(ushort_t b) {
    return __uint_as_float(((uint_t)b) << 16);
}
__device__ __forceinline__ void gld_lds16(const void* g, void* s) {
    __builtin_amdgcn_global_load_lds((const __attribute__((address_space(1))) void*)g,
                                     (__attribute__((address_space(3))) void*)s, 16, 0, 0);
}

// ------------------------------- CSR build ---------------------------------
__global__ void hist_kernel(const int* __restrict__ dst, int* __restrict__ counts, int E) {
    int e = blockIdx.x * blockDim.x + threadIdx.x;
    if (e < E) atomicAdd(&counts[dst[e]], 1);
}

__global__ void assign_kernel(const int* __restrict__ counts, int* __restrict__ beg,
                              float* __restrict__ deg_inv, int* __restrict__ total, int n) {
    int i = blockIdx.x * blockDim.x + threadIdx.x;
    int lane = threadIdx.x & 63;
    int c = (i < n) ? counts[i] : 0;
    int s = c;
    #pragma unroll
    for (int off = 1; off < 64; off <<= 1) {
        int t = __shfl_up(s, off);
        if (lane >= off) s += t;
    }
    int wtot = __shfl(s, 63);
    int wbase = 0;
    if (lane == 63) wbase = atomicAdd(total, wtot);
    wbase = __shfl(wbase, 63);
    if (i < n) {
        beg[i] = wbase + s - c;
        deg_inv[i] = (c > 0) ? 1.0f / (float)c : 0.0f;
    }
}

__global__ void scatter_kernel(const int* __restrict__ edge_index,
                               const float* __restrict__ edge_attr,
                               const int* __restrict__ beg,
                               int* __restrict__ cursor,
                               int2* __restrict__ pk, int E) {
    int e = blockIdx.x * blockDim.x + threadIdx.x;
    if (e >= E) return;
    int s = edge_index[e];
    int d = edge_index[E + e];
    int pos = beg[d] + atomicAdd(&cursor[d], 1);
    int2 v; v.x = s; v.y = __float_as_int(edge_attr[e]);
    pk[pos] = v;
}

// ------------------------------ precision prep -----------------------------
// split f32 array into bf16 hi/lo arrays (4 elems/thread)
__global__ void split_kernel(const float* __restrict__ in, ushort_t* __restrict__ oh,
                             ushort_t* __restrict__ ol, int total4) {
    int i = blockIdx.x * blockDim.x + threadIdx.x;
    if (i >= total4) return;
    float4 v = *reinterpret_cast<const float4*>(&in[(size_t)i * 4]);
    ushort_t h0 = f2bf(v.x), h1 = f2bf(v.y), h2 = f2bf(v.z), h3 = f2bf(v.w);
    ushort_t l0 = f2bf(v.x - bf2f(h0)), l1 = f2bf(v.y - bf2f(h1));
    ushort_t l2 = f2bf(v.z - bf2f(h2)), l3 = f2bf(v.w - bf2f(h3));
    uint_t hw0 = (uint_t)h0 | ((uint_t)h1 << 16), hw1 = (uint_t)h2 | ((uint_t)h3 << 16);
    uint_t lw0 = (uint_t)l0 | ((uint_t)l1 << 16), lw1 = (uint_t)l2 | ((uint_t)l3 << 16);
    *reinterpret_cast<uint2*>(&oh[(size_t)i * 4]) = make_uint2(hw0, hw1);
    *reinterpret_cast<uint2*>(&ol[(size_t)i * 4]) = make_uint2(lw0, lw1);
}

// W' = [Wrel;Wroot] (256x128) -> tiled bf16 image [kc(8)][g(4)][n(128)] of 16B
// granules; granule (kc,g,n) elem j = W'[kc*32+g*8+j][n]. 32768 threads.
__global__ void prep_w_kernel(const float* __restrict__ Wrel, const float* __restrict__ Wroot,
                              ushort_t* __restrict__ wh, ushort_t* __restrict__ wl) {
    int t = blockIdx.x * blockDim.x + threadIdx.x;
    if (t >= 32768) return;
    int q = t >> 3, j = t & 7;
    int kc = q >> 9, rem = q & 511, g = rem >> 7, nn = rem & 127;
    int k = kc * 32 + g * 8 + j;
    float v = (k < DIM) ? Wrel[k * DIM + nn] : Wroot[(k - DIM) * DIM + nn];
    ushort_t h = f2bf(v);
    wh[t] = h;
    wl[t] = f2bf(v - bf2f(h));
}

// ------------------------------- aggregate ---------------------------------
// wave per node; lane owns cols {2l, 2l+1}; feat = hi+lo bf16; unroll x8.
__global__ __launch_bounds__(256) void aggregate_kernel(
    const ushort_t* __restrict__ fh, const ushort_t* __restrict__ fl,
    const int2* __restrict__ pk,
    const int* __restrict__ beg, const int* __restrict__ counts,
    const float* __restrict__ deg_inv,
    ushort_t* __restrict__ ah, ushort_t* __restrict__ al, int n)
{
    int node = blockIdx.x * 4 + (threadIdx.x >> 6);
    if (node >= n) return;
    const int l = threadIdx.x & 63;
    int b   = __builtin_amdgcn_readfirstlane(beg[node]);
    int cnt = __builtin_amdgcn_readfirstlane(counts[node]);
    float a0 = 0.f, a1 = 0.f;
    int e = 0;
    for (; e + 8 <= cnt; e += 8) {
        int2 p[8];
        #pragma unroll
        for (int u = 0; u < 8; ++u) p[u] = pk[b + e + u];
        uint_t hb[8], lb[8];
        #pragma unroll
        for (int u = 0; u < 8; ++u) {
            size_t base = (size_t)p[u].x * DIM + l * 2;
            hb[u] = *reinterpret_cast<const uint_t*>(&fh[base]);
            lb[u] = *reinterpret_cast<const uint_t*>(&fl[base]);
        }
        #pragma unroll
        for (int u = 0; u < 8; ++u) {
            float wt = __int_as_float(p[u].y);
            float v0 = bf2f((ushort_t)hb[u]) + bf2f((ushort_t)lb[u]);
            float v1 = bf2f((ushort_t)(hb[u] >> 16)) + bf2f((ushort_t)(lb[u] >> 16));
            a0 = fmaf(v0, wt, a0);
            a1 = fmaf(v1, wt, a1);
        }
    }
    for (; e + 4 <= cnt; e += 4) {
        int2 p[4];
        #pragma unroll
        for (int u = 0; u < 4; ++u) p[u] = pk[b + e + u];
        #pragma unroll
        for (int u = 0; u < 4; ++u) {
            size_t base = (size_t)p[u].x * DIM + l * 2;
            uint_t hb = *reinterpret_cast<const uint_t*>(&fh[base]);
            uint_t lb = *reinterpret_cast<const uint_t*>(&fl[base]);
            float wt = __int_as_float(p[u].y);
            a0 = fmaf(bf2f((ushort_t)hb) + bf2f((ushort_t)lb), wt, a0);
            a1 = fmaf(bf2f((ushort_t)(hb >> 16)) + bf2f((ushort_t)(lb >> 16)), wt, a1);
        }
    }
    for (; e < cnt; ++e) {
        int2 p = pk[b + e];
        size_t base = (size_t)p.x * DIM + l * 2;
        uint_t hb = *reinterpret_cast<const uint_t*>(&fh[base]);
        uint_t lb = *reinterpret_cast<const uint_t*>(&fl[base]);
        float wt = __int_as_float(p.y);
        a0 = fmaf(bf2f((ushort_t)hb) + bf2f((ushort_t)lb), wt, a0);
        a1 = fmaf(bf2f((ushort_t)(hb >> 16)) + bf2f((ushort_t)(lb >> 16)), wt, a1);
    }
    float di = deg_inv[node];
    a0 *= di; a1 *= di;
    ushort_t h0 = f2bf(a0), h1 = f2bf(a1);
    uint_t hw = (uint_t)h0 | ((uint_t)h1 << 16);
    uint_t lw = (uint_t)f2bf(a0 - bf2f(h0)) | ((uint_t)f2bf(a1 - bf2f(h1)) << 16);
    size_t o = (size_t)node * DIM + l * 2;
    *reinterpret_cast<uint_t*>(&ah[o]) = hw;
    *reinterpret_cast<uint_t*>(&al[o]) = lw;
}

// ------------------------------- MFMA GEMM ---------------------------------
// C[128 tile][128] = relu(sum_kc A'[.,kc]*W'[kc,.] + b), A' = [agg|in] K=256,
// 3-term split. LDS per buffer: Ah,Al,Wh,Wl sections of 8KB, granule layout
// [g(4)][r(128)] 16B granules. Wave w stages section w (8x global_load_lds).
__global__ __launch_bounds__(256, 2) void gemm_mfma(
    const ushort_t* __restrict__ inh, const ushort_t* __restrict__ inl,
    const ushort_t* __restrict__ aggh, const ushort_t* __restrict__ aggl,
    const ushort_t* __restrict__ wh, const ushort_t* __restrict__ wl,
    const float* __restrict__ bias,
    float* __restrict__ outf, ushort_t* __restrict__ outh, ushort_t* __restrict__ outl,
    int n)
{
    __shared__ ushort_t lds[2][4][4096];   // 64 KB
    const int tid = threadIdx.x;
    const int l = tid & 63;
    const int w = tid >> 6;
    const int m0 = blockIdx.x * 128;
    const int lr = l & 15, lg = l >> 4;
    const int rbase = (w >> 1) * 64, cbase = (w & 1) * 64;

    f32x4 acc[4][4];
    #pragma unroll
    for (int a = 0; a < 4; ++a)
        #pragma unroll
        for (int b = 0; b < 4; ++b) acc[a][b] = (f32x4){0.f, 0.f, 0.f, 0.f};

    auto stage = [&](int buf, int kc) {
        if (w < 2) {
            const ushort_t* src = (kc < 4) ? (w ? aggl : aggh) : (w ? inl : inh);
            const int kcl = (kc & 3) * 32;
            #pragma unroll
            for (int i = 0; i < 8; ++i) {
                int r = ((i & 1) << 6) + l;     // slot q = i*64+l -> g=i>>1, r
                int g = i >> 1;
                gld_lds16(src + (size_t)(m0 + r) * DIM + kcl + g * 8,
                          &lds[buf][w][i << 9]);
            }
        } else {
            const ushort_t* src = ((w == 2) ? wh : wl) + (size_t)kc * 4096;
            #pragma unroll
            for (int i = 0; i < 8; ++i)
                gld_lds16(src + (size_t)(((i << 6) + l) * 8), &lds[buf][w][i << 9]);
        }
    };

    stage(0, 0);
    __syncthreads();
    int cur = 0;
    for (int kc = 0; kc < 8; ++kc) {
        if (kc < 7) stage(cur ^ 1, kc + 1);
        bf16x8 fah[4], fal[4], fwh[4], fwl[4];
        #pragma unroll
        for (int f = 0; f < 4; ++f) {
            int ar = rbase + f * 16 + lr;
            fah[f] = *reinterpret_cast<const bf16x8*>(&lds[cur][0][(lg * 128 + ar) * 8]);
            fal[f] = *reinterpret_cast<const bf16x8*>(&lds[cur][1][(lg * 128 + ar) * 8]);
            int cn = cbase + f * 16 + lr;
            fwh[f] = *reinterpret_cast<const bf16x8*>(&lds[cur][2][(lg * 128 + cn) * 8]);
            fwl[f] = *reinterpret_cast<const bf16x8*>(&lds[cur][3][(lg * 128 + cn) * 8]);
        }
        #pragma unroll
        for (int fm = 0; fm < 4; ++fm)
            #pragma unroll
            for (int fn = 0; fn < 4; ++fn) {
                acc[fm][fn] = __builtin_amdgcn_mfma_f32_16x16x32_bf16(fah[fm], fwh[fn], acc[fm][fn], 0, 0, 0);
                acc[fm][fn] = __builtin_amdgcn_mfma_f32_16x16x32_bf16(fah[fm], fwl[fn], acc[fm][fn], 0, 0, 0);
                acc[fm][fn] = __builtin_amdgcn_mfma_f32_16x16x32_bf16(fal[fm], fwh[fn], acc[fm][fn], 0, 0, 0);
            }
        __syncthreads();
        cur ^= 1;
    }

    #pragma unroll
    for (int fn = 0; fn < 4; ++fn) {
        int col = cbase + fn * 16 + lr;
        float bv = bias[col];
        #pragma unroll
        for (int fm = 0; fm < 4; ++fm) {
            int row0 = m0 + rbase + fm * 16 + lg * 4;
            #pragma unroll
            for (int e = 0; e < 4; ++e) {
                int row = row0 + e;
                if (row < n) {
                    float v = fmaxf(acc[fm][fn][e] + bv, 0.f);
                    size_t o = (size_t)row * DIM + col;
                    if (outf) outf[o] = v;
                    if (outh) {
                        ushort_t hb = f2bf(v);
                        outh[o] = hb;
                        outl[o] = f2bf(v - bf2f(hb));
                    }
                }
            }
        }
    }
}

// --------------------------------- launch ----------------------------------
extern "C" void kernel_launch(void* const* d_in, const int* in_sizes, int n_in,
                              void* d_out, int out_size, void* d_ws, size_t ws_size,
                              hipStream_t stream) {
    const float* x          = (const float*)d_in[0];
    const int*   edge_index = (const int*)d_in[1];
    const float* edge_attr  = (const float*)d_in[2];
    const float* Wrel1 = (const float*)d_in[3];
    const float* b1    = (const float*)d_in[4];
    const float* Wroot1= (const float*)d_in[5];
    const float* Wrel2 = (const float*)d_in[6];
    const float* b2    = (const float*)d_in[7];
    const float* Wroot2= (const float*)d_in[8];
    const float* Wrel3 = (const float*)d_in[9];
    const float* b3    = (const float*)d_in[10];
    const float* Wroot3= (const float*)d_in[11];

    const int N = in_sizes[0] / DIM;
    const int E = in_sizes[2];
    const size_t ND = (size_t)N * DIM;

    size_t off = 0;
    auto carve = [&](size_t bytes) -> char* {
        char* p = (char*)d_ws + off;
        off = (off + bytes + 255) & ~(size_t)255;
        return p;
    };
    int*   counts  = (int*)  carve((size_t)N * 4);
    int*   cursor  = (int*)  carve((size_t)N * 4);
    int*   total   = (int*)  carve(256);
    size_t zero_end = off;
    int*   begb    = (int*)  carve((size_t)N * 4);
    float* deg_inv = (float*)carve((size_t)N * 4);
    int2*  pk      = (int2*) carve((size_t)E * 8);
    ushort_t* w1h = (ushort_t*)carve(65536);
    ushort_t* w1l = (ushort_t*)carve(65536);
    ushort_t* w2h = (ushort_t*)carve(65536);
    ushort_t* w2l = (ushort_t*)carve(65536);
    ushort_t* w3h = (ushort_t*)carve(65536);
    ushort_t* w3l = (ushort_t*)carve(65536);
    ushort_t* gh  = (ushort_t*)carve(ND * 2);   // agg hi
    ushort_t* gl  = (ushort_t*)carve(ND * 2);   // agg lo
    ushort_t* fxh = (ushort_t*)carve(ND * 2);   // x split -> later gemm2 out
    ushort_t* fxl = (ushort_t*)carve(ND * 2);
    ushort_t* f1h = (ushort_t*)carve(ND * 2);   // gemm1 out
    ushort_t* f1l = (ushort_t*)carve(ND * 2);
    carve(32768);                               // pad for OOB tile staging reads
    (void)ws_size; (void)n_in; (void)out_size;

    // CSR build
    hipMemsetAsync(counts, 0, zero_end, stream);
    hist_kernel<<<(E + 255) / 256, 256, 0, stream>>>(edge_index + E, counts, E);
    assign_kernel<<<(N + 255) / 256, 256, 0, stream>>>(counts, begb, deg_inv, total, N);
    scatter_kernel<<<(E + 255) / 256, 256, 0, stream>>>(edge_index, edge_attr, begb, cursor, pk, E);

    // precision prep
    split_kernel<<<(int)((ND / 4 + 255) / 256), 256, 0, stream>>>(x, fxh, fxl, (int)(ND / 4));
    prep_w_kernel<<<128, 256, 0, stream>>>(Wrel1, Wroot1, w1h, w1l);
    prep_w_kernel<<<128, 256, 0, stream>>>(Wrel2, Wroot2, w2h, w2l);
    prep_w_kernel<<<128, 256, 0, stream>>>(Wrel3, Wroot3, w3h, w3l);

    dim3 aggGrid((N + 3) / 4);
    dim3 gemmGrid((N + 127) / 128);

    // Layer 1
    aggregate_kernel<<<aggGrid, 256, 0, stream>>>(fxh, fxl, pk, begb, counts, deg_inv, gh, gl, N);
    gemm_mfma<<<gemmGrid, 256, 0, stream>>>(fxh, fxl, gh, gl, w1h, w1l, b1,
                                            nullptr, f1h, f1l, N);
    // Layer 2 (writes over fx, which is dead after gemm1)
    aggregate_kernel<<<aggGrid, 256, 0, stream>>>(f1h, f1l, pk, begb, counts, deg_inv, gh, gl, N);
    gemm_mfma<<<gemmGrid, 256, 0, stream>>>(f1h, f1l, gh, gl, w2h, w2l, b2,
                                            nullptr, fxh, fxl, N);
    // Layer 3 (final f32 output only)
    aggregate_kernel<<<aggGrid, 256, 0, stream>>>(fxh, fxl, pk, begb, counts, deg_inv, gh, gl, N);
    gemm_mfma<<<gemmGrid, 256, 0, stream>>>(fxh, fxl, gh, gl, w3h, w3l, b3,
                                            (float*)d_out, nullptr, nullptr, N);
}

// Round 5
// 660.524 us; speedup vs baseline: 3.4128x; 1.3046x over previous
//
#include <hip/hip_runtime.h>
#include <hip/hip_bf16.h>

// ---------------------------------------------------------------------------
// GNN: 3x GraphConv(mean, edge-weighted), N=100k, E=1.6M, D=H=128.
//   CSR build: histogram (atomicAdd returns per-dst rank) -> wave-scan+atomic
//              base -> rank-indexed scatter (no second atomic pass).
//   aggregate: wave per node, gathers bf16 HI feature rows only (256B/edge,
//              halves gather traffic; lo refinement dropped -- error budget ok),
//              writes agg as bf16 hi/lo.
//   GEMM: bf16 MFMA 16x16x32, 3-term split (Ah*Wh + Ah*Wl + Al*Wh), 128x128
//         tile, 4 waves x 4x4 frags, double-buffered LDS via global_load_lds,
//         granule-transposed LDS layout (conflict-free ds_read_b128).
// ---------------------------------------------------------------------------

#define DIM 128
typedef unsigned short ushort_t;
typedef unsigned int uint_t;
typedef __attribute__((ext_vector_type(8))) short bf16x8;
typedef __attribute__((ext_vector_type(4))) float f32x4;

__device__ __forceinline__ ushort_t f2bf(float x) {           // RNE bf16 bits
    uint_t u = __float_as_uint(x);
    u = (u + 0x7fff + ((u >> 16) & 1)) >> 16;
    return (ushort_t)u;
}
__device__ __forceinline__ float bf2f(ushort_t b) {
    return __uint_as_float(((uint_t)b) << 16);
}
__device__ __forceinline__ void gld_lds16(const void* g, void* s) {
    __builtin_amdgcn_global_load_lds((const __attribute__((address_space(1))) void*)g,
                                     (__attribute__((address_space(3))) void*)s, 16, 0, 0);
}

// ------------------------------- CSR build ---------------------------------
// atomicAdd's return value = this edge's rank within its dst segment.
__global__ void hist_kernel(const int* __restrict__ dst, int* __restrict__ counts,
                            int* __restrict__ rank, int E) {
    int e = blockIdx.x * blockDim.x + threadIdx.x;
    if (e < E) rank[e] = atomicAdd(&counts[dst[e]], 1);
}

__global__ void assign_kernel(const int* __restrict__ counts, int* __restrict__ beg,
                              float* __restrict__ deg_inv, int* __restrict__ total, int n) {
    int i = blockIdx.x * blockDim.x + threadIdx.x;
    int lane = threadIdx.x & 63;
    int c = (i < n) ? counts[i] : 0;
    int s = c;
    #pragma unroll
    for (int off = 1; off < 64; off <<= 1) {
        int t = __shfl_up(s, off);
        if (lane >= off) s += t;
    }
    int wtot = __shfl(s, 63);
    int wbase = 0;
    if (lane == 63) wbase = atomicAdd(total, wtot);
    wbase = __shfl(wbase, 63);
    if (i < n) {
        beg[i] = wbase + s - c;
        deg_inv[i] = (c > 0) ? 1.0f / (float)c : 0.0f;
    }
}

__global__ void scatter_kernel(const int* __restrict__ edge_index,
                               const float* __restrict__ edge_attr,
                               const int* __restrict__ beg,
                               const int* __restrict__ rank,
                               int2* __restrict__ pk, int E) {
    int e = blockIdx.x * blockDim.x + threadIdx.x;
    if (e >= E) return;
    int s = edge_index[e];
    int d = edge_index[E + e];
    int pos = beg[d] + rank[e];
    int2 v; v.x = s; v.y = __float_as_int(edge_attr[e]);
    pk[pos] = v;
}

// ------------------------------ precision prep -----------------------------
__global__ void split_kernel(const float* __restrict__ in, ushort_t* __restrict__ oh,
                             ushort_t* __restrict__ ol, int total4) {
    int i = blockIdx.x * blockDim.x + threadIdx.x;
    if (i >= total4) return;
    float4 v = *reinterpret_cast<const float4*>(&in[(size_t)i * 4]);
    ushort_t h0 = f2bf(v.x), h1 = f2bf(v.y), h2 = f2bf(v.z), h3 = f2bf(v.w);
    ushort_t l0 = f2bf(v.x - bf2f(h0)), l1 = f2bf(v.y - bf2f(h1));
    ushort_t l2 = f2bf(v.z - bf2f(h2)), l3 = f2bf(v.w - bf2f(h3));
    uint_t hw0 = (uint_t)h0 | ((uint_t)h1 << 16), hw1 = (uint_t)h2 | ((uint_t)h3 << 16);
    uint_t lw0 = (uint_t)l0 | ((uint_t)l1 << 16), lw1 = (uint_t)l2 | ((uint_t)l3 << 16);
    *reinterpret_cast<uint2*>(&oh[(size_t)i * 4]) = make_uint2(hw0, hw1);
    *reinterpret_cast<uint2*>(&ol[(size_t)i * 4]) = make_uint2(lw0, lw1);
}

// W' = [Wrel;Wroot] (256x128) -> tiled bf16 image [kc(8)][g(4)][n(128)] of 16B
// granules; granule (kc,g,n) elem j = W'[kc*32+g*8+j][n].
__global__ void prep_w_kernel(const float* __restrict__ Wrel, const float* __restrict__ Wroot,
                              ushort_t* __restrict__ wh, ushort_t* __restrict__ wl) {
    int t = blockIdx.x * blockDim.x + threadIdx.x;
    if (t >= 32768) return;
    int q = t >> 3, j = t & 7;
    int kc = q >> 9, rem = q & 511, g = rem >> 7, nn = rem & 127;
    int k = kc * 32 + g * 8 + j;
    float v = (k < DIM) ? Wrel[k * DIM + nn] : Wroot[(k - DIM) * DIM + nn];
    ushort_t h = f2bf(v);
    wh[t] = h;
    wl[t] = f2bf(v - bf2f(h));
}

// ------------------------------- aggregate ---------------------------------
// wave per node; lane owns cols {2l, 2l+1}; gathers HI rows only; unroll x8.
__global__ __launch_bounds__(256) void aggregate_kernel(
    const ushort_t* __restrict__ fh,
    const int2* __restrict__ pk,
    const int* __restrict__ beg, const int* __restrict__ counts,
    const float* __restrict__ deg_inv,
    ushort_t* __restrict__ ah, ushort_t* __restrict__ al, int n)
{
    int node = blockIdx.x * 4 + (threadIdx.x >> 6);
    if (node >= n) return;
    const int l = threadIdx.x & 63;
    int b   = __builtin_amdgcn_readfirstlane(beg[node]);
    int cnt = __builtin_amdgcn_readfirstlane(counts[node]);
    float a0 = 0.f, a1 = 0.f;
    int e = 0;
    for (; e + 8 <= cnt; e += 8) {
        int2 p[8];
        #pragma unroll
        for (int u = 0; u < 8; ++u) p[u] = pk[b + e + u];
        uint_t hb[8];
        #pragma unroll
        for (int u = 0; u < 8; ++u)
            hb[u] = *reinterpret_cast<const uint_t*>(&fh[(size_t)p[u].x * DIM + l * 2]);
        #pragma unroll
        for (int u = 0; u < 8; ++u) {
            float wt = __int_as_float(p[u].y);
            a0 = fmaf(bf2f((ushort_t)hb[u]), wt, a0);
            a1 = fmaf(bf2f((ushort_t)(hb[u] >> 16)), wt, a1);
        }
    }
    for (; e + 4 <= cnt; e += 4) {
        int2 p[4];
        #pragma unroll
        for (int u = 0; u < 4; ++u) p[u] = pk[b + e + u];
        #pragma unroll
        for (int u = 0; u < 4; ++u) {
            uint_t hb = *reinterpret_cast<const uint_t*>(&fh[(size_t)p[u].x * DIM + l * 2]);
            float wt = __int_as_float(p[u].y);
            a0 = fmaf(bf2f((ushort_t)hb), wt, a0);
            a1 = fmaf(bf2f((ushort_t)(hb >> 16)), wt, a1);
        }
    }
    for (; e < cnt; ++e) {
        int2 p = pk[b + e];
        uint_t hb = *reinterpret_cast<const uint_t*>(&fh[(size_t)p.x * DIM + l * 2]);
        float wt = __int_as_float(p.y);
        a0 = fmaf(bf2f((ushort_t)hb), wt, a0);
        a1 = fmaf(bf2f((ushort_t)(hb >> 16)), wt, a1);
    }
    float di = deg_inv[node];
    a0 *= di; a1 *= di;
    ushort_t h0 = f2bf(a0), h1 = f2bf(a1);
    uint_t hw = (uint_t)h0 | ((uint_t)h1 << 16);
    uint_t lw = (uint_t)f2bf(a0 - bf2f(h0)) | ((uint_t)f2bf(a1 - bf2f(h1)) << 16);
    size_t o = (size_t)node * DIM + l * 2;
    *reinterpret_cast<uint_t*>(&ah[o]) = hw;
    *reinterpret_cast<uint_t*>(&al[o]) = lw;
}

// ------------------------------- MFMA GEMM ---------------------------------
// C[128 tile][128] = relu(sum_kc A'[.,kc]*W'[kc,.] + b), A' = [agg|in] K=256,
// 3-term split. LDS per buffer: Ah,Al,Wh,Wl sections of 8KB, granule layout
// [g(4)][r(128)] 16B granules. Wave w stages section w (8x global_load_lds).
__global__ __launch_bounds__(256, 2) void gemm_mfma(
    const ushort_t* __restrict__ inh, const ushort_t* __restrict__ inl,
    const ushort_t* __restrict__ aggh, const ushort_t* __restrict__ aggl,
    const ushort_t* __restrict__ wh, const ushort_t* __restrict__ wl,
    const float* __restrict__ bias,
    float* __restrict__ outf, ushort_t* __restrict__ outh, ushort_t* __restrict__ outl,
    int n)
{
    __shared__ ushort_t lds[2][4][4096];   // 64 KB
    const int tid = threadIdx.x;
    const int l = tid & 63;
    const int w = tid >> 6;
    const int m0 = blockIdx.x * 128;
    const int lr = l & 15, lg = l >> 4;
    const int rbase = (w >> 1) * 64, cbase = (w & 1) * 64;

    f32x4 acc[4][4];
    #pragma unroll
    for (int a = 0; a < 4; ++a)
        #pragma unroll
        for (int b = 0; b < 4; ++b) acc[a][b] = (f32x4){0.f, 0.f, 0.f, 0.f};

    auto stage = [&](int buf, int kc) {
        if (w < 2) {
            const ushort_t* src = (kc < 4) ? (w ? aggl : aggh) : (w ? inl : inh);
            const int kcl = (kc & 3) * 32;
            #pragma unroll
            for (int i = 0; i < 8; ++i) {
                int r = ((i & 1) << 6) + l;     // slot q = i*64+l -> g=i>>1, r
                int g = i >> 1;
                gld_lds16(src + (size_t)(m0 + r) * DIM + kcl + g * 8,
                          &lds[buf][w][i << 9]);
            }
        } else {
            const ushort_t* src = ((w == 2) ? wh : wl) + (size_t)kc * 4096;
            #pragma unroll
            for (int i = 0; i < 8; ++i)
                gld_lds16(src + (size_t)(((i << 6) + l) * 8), &lds[buf][w][i << 9]);
        }
    };

    stage(0, 0);
    __syncthreads();
    int cur = 0;
    for (int kc = 0; kc < 8; ++kc) {
        if (kc < 7) stage(cur ^ 1, kc + 1);
        bf16x8 fah[4], fal[4], fwh[4], fwl[4];
        #pragma unroll
        for (int f = 0; f < 4; ++f) {
            int ar = rbase + f * 16 + lr;
            fah[f] = *reinterpret_cast<const bf16x8*>(&lds[cur][0][(lg * 128 + ar) * 8]);
            fal[f] = *reinterpret_cast<const bf16x8*>(&lds[cur][1][(lg * 128 + ar) * 8]);
            int cn = cbase + f * 16 + lr;
            fwh[f] = *reinterpret_cast<const bf16x8*>(&lds[cur][2][(lg * 128 + cn) * 8]);
            fwl[f] = *reinterpret_cast<const bf16x8*>(&lds[cur][3][(lg * 128 + cn) * 8]);
        }
        #pragma unroll
        for (int fm = 0; fm < 4; ++fm)
            #pragma unroll
            for (int fn = 0; fn < 4; ++fn) {
                acc[fm][fn] = __builtin_amdgcn_mfma_f32_16x16x32_bf16(fah[fm], fwh[fn], acc[fm][fn], 0, 0, 0);
                acc[fm][fn] = __builtin_amdgcn_mfma_f32_16x16x32_bf16(fah[fm], fwl[fn], acc[fm][fn], 0, 0, 0);
                acc[fm][fn] = __builtin_amdgcn_mfma_f32_16x16x32_bf16(fal[fm], fwh[fn], acc[fm][fn], 0, 0, 0);
            }
        __syncthreads();
        cur ^= 1;
    }

    #pragma unroll
    for (int fn = 0; fn < 4; ++fn) {
        int col = cbase + fn * 16 + lr;
        float bv = bias[col];
        #pragma unroll
        for (int fm = 0; fm < 4; ++fm) {
            int row0 = m0 + rbase + fm * 16 + lg * 4;
            #pragma unroll
            for (int e = 0; e < 4; ++e) {
                int row = row0 + e;
                if (row < n) {
                    float v = fmaxf(acc[fm][fn][e] + bv, 0.f);
                    size_t o = (size_t)row * DIM + col;
                    if (outf) outf[o] = v;
                    if (outh) {
                        ushort_t hb = f2bf(v);
                        outh[o] = hb;
                        outl[o] = f2bf(v - bf2f(hb));
                    }
                }
            }
        }
    }
}

// --------------------------------- launch ----------------------------------
extern "C" void kernel_launch(void* const* d_in, const int* in_sizes, int n_in,
                              void* d_out, int out_size, void* d_ws, size_t ws_size,
                              hipStream_t stream) {
    const float* x          = (const float*)d_in[0];
    const int*   edge_index = (const int*)d_in[1];
    const float* edge_attr  = (const float*)d_in[2];
    const float* Wrel1 = (const float*)d_in[3];
    const float* b1    = (const float*)d_in[4];
    const float* Wroot1= (const float*)d_in[5];
    const float* Wrel2 = (const float*)d_in[6];
    const float* b2    = (const float*)d_in[7];
    const float* Wroot2= (const float*)d_in[8];
    const float* Wrel3 = (const float*)d_in[9];
    const float* b3    = (const float*)d_in[10];
    const float* Wroot3= (const float*)d_in[11];

    const int N = in_sizes[0] / DIM;
    const int E = in_sizes[2];
    const size_t ND = (size_t)N * DIM;

    size_t off = 0;
    auto carve = [&](size_t bytes) -> char* {
        char* p = (char*)d_ws + off;
        off = (off + bytes + 255) & ~(size_t)255;
        return p;
    };
    int*   counts  = (int*)  carve((size_t)N * 4);
    int*   total   = (int*)  carve(256);
    size_t zero_end = off;
    int*   begb    = (int*)  carve((size_t)N * 4);
    float* deg_inv = (float*)carve((size_t)N * 4);
    int*   rank    = (int*)  carve((size_t)E * 4);
    int2*  pk      = (int2*) carve((size_t)E * 8);
    ushort_t* w1h = (ushort_t*)carve(65536);
    ushort_t* w1l = (ushort_t*)carve(65536);
    ushort_t* w2h = (ushort_t*)carve(65536);
    ushort_t* w2l = (ushort_t*)carve(65536);
    ushort_t* w3h = (ushort_t*)carve(65536);
    ushort_t* w3l = (ushort_t*)carve(65536);
    ushort_t* gh  = (ushort_t*)carve(ND * 2);   // agg hi
    ushort_t* gl  = (ushort_t*)carve(ND * 2);   // agg lo
    ushort_t* fxh = (ushort_t*)carve(ND * 2);   // x split -> later gemm2 out
    ushort_t* fxl = (ushort_t*)carve(ND * 2);
    ushort_t* f1h = (ushort_t*)carve(ND * 2);   // gemm1 out
    ushort_t* f1l = (ushort_t*)carve(ND * 2);
    carve(32768);                               // pad for OOB tile staging reads
    (void)ws_size; (void)n_in; (void)out_size;

    // CSR build
    hipMemsetAsync(counts, 0, zero_end, stream);
    hist_kernel<<<(E + 255) / 256, 256, 0, stream>>>(edge_index + E, counts, rank, E);
    assign_kernel<<<(N + 255) / 256, 256, 0, stream>>>(counts, begb, deg_inv, total, N);
    scatter_kernel<<<(E + 255) / 256, 256, 0, stream>>>(edge_index, edge_attr, begb, rank, pk, E);

    // precision prep
    split_kernel<<<(int)((ND / 4 + 255) / 256), 256, 0, stream>>>(x, fxh, fxl, (int)(ND / 4));
    prep_w_kernel<<<128, 256, 0, stream>>>(Wrel1, Wroot1, w1h, w1l);
    prep_w_kernel<<<128, 256, 0, stream>>>(Wrel2, Wroot2, w2h, w2l);
    prep_w_kernel<<<128, 256, 0, stream>>>(Wrel3, Wroot3, w3h, w3l);

    dim3 aggGrid((N + 3) / 4);
    dim3 gemmGrid((N + 127) / 128);

    // Layer 1
    aggregate_kernel<<<aggGrid, 256, 0, stream>>>(fxh, pk, begb, counts, deg_inv, gh, gl, N);
    gemm_mfma<<<gemmGrid, 256, 0, stream>>>(fxh, fxl, gh, gl, w1h, w1l, b1,
                                            nullptr, f1h, f1l, N);
    // Layer 2 (writes over fx, which is dead after gemm1)
    aggregate_kernel<<<aggGrid, 256, 0, stream>>>(f1h, pk, begb, counts, deg_inv, gh, gl, N);
    gemm_mfma<<<gemmGrid, 256, 0, stream>>>(f1h, f1l, gh, gl, w2h, w2l, b2,
                                            nullptr, fxh, fxl, N);
    // Layer 3 (final f32 output only)
    aggregate_kernel<<<aggGrid, 256, 0, stream>>>(fxh, pk, begb, counts, deg_inv, gh, gl, N);
    gemm_mfma<<<gemmGrid, 256, 0, stream>>>(fxh, fxl, gh, gl, w3h, w3l, b3,
                                            (float*)d_out, nullptr, nullptr, N);
}

// Round 6
// 547.298 us; speedup vs baseline: 4.1188x; 1.2069x over previous
//
#include <hip/hip_runtime.h>
#include <hip/hip_bf16.h>
#include <hip/hip_fp16.h>

// ---------------------------------------------------------------------------
// GNN: 3x GraphConv(mean, edge-weighted), N=100k, E=1.6M, D=H=128.
//   CSR build: histogram (atomicAdd returns per-dst rank) -> wave-scan+atomic
//              base -> rank-indexed scatter (no second atomic pass).
//   All features fp16 (11-bit mantissa; fp16*fp16 exact in f32 MFMA accum).
//   aggregate: wave per node, gathers fp16 rows (256B/edge), f32 math,
//              writes fp16 agg.
//   GEMM: single-term fp16 MFMA 16x16x32, 128x128 tile, 4 waves x 4x4 frags,
//         32KB LDS double-buffered via global_load_lds -> 4 blocks/CU.
// ---------------------------------------------------------------------------

#define DIM 128
typedef unsigned short ushort_t;
typedef unsigned int uint_t;
typedef __attribute__((ext_vector_type(8))) _Float16 f16x8;
typedef __attribute__((ext_vector_type(4))) float f32x4;

__device__ __forceinline__ ushort_t f2h(float x) {
    return __half_as_ushort(__float2half(x));
}
__device__ __forceinline__ float h2f(ushort_t b) {
    return __half2float(__ushort_as_half(b));
}
__device__ __forceinline__ void gld_lds16(const void* g, void* s) {
    __builtin_amdgcn_global_load_lds((const __attribute__((address_space(1))) void*)g,
                                     (__attribute__((address_space(3))) void*)s, 16, 0, 0);
}

// ------------------------------- CSR build ---------------------------------
__global__ void hist_kernel(const int* __restrict__ dst, int* __restrict__ counts,
                            int* __restrict__ rank, int E) {
    int e = blockIdx.x * blockDim.x + threadIdx.x;
    if (e < E) rank[e] = atomicAdd(&counts[dst[e]], 1);
}

__global__ void assign_kernel(const int* __restrict__ counts, int* __restrict__ beg,
                              float* __restrict__ deg_inv, int* __restrict__ total, int n) {
    int i = blockIdx.x * blockDim.x + threadIdx.x;
    int lane = threadIdx.x & 63;
    int c = (i < n) ? counts[i] : 0;
    int s = c;
    #pragma unroll
    for (int off = 1; off < 64; off <<= 1) {
        int t = __shfl_up(s, off);
        if (lane >= off) s += t;
    }
    int wtot = __shfl(s, 63);
    int wbase = 0;
    if (lane == 63) wbase = atomicAdd(total, wtot);
    wbase = __shfl(wbase, 63);
    if (i < n) {
        beg[i] = wbase + s - c;
        deg_inv[i] = (c > 0) ? 1.0f / (float)c : 0.0f;
    }
}

__global__ void scatter_kernel(const int* __restrict__ edge_index,
                               const float* __restrict__ edge_attr,
                               const int* __restrict__ beg,
                               const int* __restrict__ rank,
                               int2* __restrict__ pk, int E) {
    int e = blockIdx.x * blockDim.x + threadIdx.x;
    if (e >= E) return;
    int s = edge_index[e];
    int d = edge_index[E + e];
    int pos = beg[d] + rank[e];
    int2 v; v.x = s; v.y = __float_as_int(edge_attr[e]);
    pk[pos] = v;
}

// ------------------------------ precision prep -----------------------------
// f32 -> fp16, 4 elems/thread
__global__ void cvt_kernel(const float* __restrict__ in, ushort_t* __restrict__ oh, int total4) {
    int i = blockIdx.x * blockDim.x + threadIdx.x;
    if (i >= total4) return;
    float4 v = *reinterpret_cast<const float4*>(&in[(size_t)i * 4]);
    ushort4 o;
    o.x = f2h(v.x); o.y = f2h(v.y); o.z = f2h(v.z); o.w = f2h(v.w);
    *reinterpret_cast<ushort4*>(&oh[(size_t)i * 4]) = o;
}

// W' = [Wrel;Wroot] (256x128) -> tiled fp16 image [kc(8)][g(4)][n(128)] of 16B
// granules; granule (kc,g,n) elem j = W'[kc*32+g*8+j][n].
__global__ void prep_w_kernel(const float* __restrict__ Wrel, const float* __restrict__ Wroot,
                              ushort_t* __restrict__ wimg) {
    int t = blockIdx.x * blockDim.x + threadIdx.x;
    if (t >= 32768) return;
    int q = t >> 3, j = t & 7;
    int kc = q >> 9, rem = q & 511, g = rem >> 7, nn = rem & 127;
    int k = kc * 32 + g * 8 + j;
    float v = (k < DIM) ? Wrel[k * DIM + nn] : Wroot[(k - DIM) * DIM + nn];
    wimg[t] = f2h(v);
}

// ------------------------------- aggregate ---------------------------------
// wave per node; lane owns cols {2l, 2l+1}; gathers fp16 rows; unroll x8.
__global__ __launch_bounds__(256) void aggregate_kernel(
    const ushort_t* __restrict__ fh,
    const int2* __restrict__ pk,
    const int* __restrict__ beg, const int* __restrict__ counts,
    const float* __restrict__ deg_inv,
    ushort_t* __restrict__ ah, int n)
{
    int node = blockIdx.x * 4 + (threadIdx.x >> 6);
    if (node >= n) return;
    const int l = threadIdx.x & 63;
    int b   = __builtin_amdgcn_readfirstlane(beg[node]);
    int cnt = __builtin_amdgcn_readfirstlane(counts[node]);
    float a0 = 0.f, a1 = 0.f;
    int e = 0;
    for (; e + 8 <= cnt; e += 8) {
        int2 p[8];
        #pragma unroll
        for (int u = 0; u < 8; ++u) p[u] = pk[b + e + u];
        uint_t hb[8];
        #pragma unroll
        for (int u = 0; u < 8; ++u)
            hb[u] = *reinterpret_cast<const uint_t*>(&fh[(size_t)p[u].x * DIM + l * 2]);
        #pragma unroll
        for (int u = 0; u < 8; ++u) {
            float wt = __int_as_float(p[u].y);
            a0 = fmaf(h2f((ushort_t)hb[u]), wt, a0);
            a1 = fmaf(h2f((ushort_t)(hb[u] >> 16)), wt, a1);
        }
    }
    for (; e + 4 <= cnt; e += 4) {
        int2 p[4];
        #pragma unroll
        for (int u = 0; u < 4; ++u) p[u] = pk[b + e + u];
        #pragma unroll
        for (int u = 0; u < 4; ++u) {
            uint_t hb = *reinterpret_cast<const uint_t*>(&fh[(size_t)p[u].x * DIM + l * 2]);
            float wt = __int_as_float(p[u].y);
            a0 = fmaf(h2f((ushort_t)hb), wt, a0);
            a1 = fmaf(h2f((ushort_t)(hb >> 16)), wt, a1);
        }
    }
    for (; e < cnt; ++e) {
        int2 p = pk[b + e];
        uint_t hb = *reinterpret_cast<const uint_t*>(&fh[(size_t)p.x * DIM + l * 2]);
        float wt = __int_as_float(p.y);
        a0 = fmaf(h2f((ushort_t)hb), wt, a0);
        a1 = fmaf(h2f((ushort_t)(hb >> 16)), wt, a1);
    }
    float di = deg_inv[node];
    a0 *= di; a1 *= di;
    uint_t hw = (uint_t)f2h(a0) | ((uint_t)f2h(a1) << 16);
    *reinterpret_cast<uint_t*>(&ah[(size_t)node * DIM + l * 2]) = hw;
}

// ------------------------------- MFMA GEMM ---------------------------------
// C[128 tile][128] = relu(sum_kc A'[.,kc]*W'[kc,.] + b), A' = [agg|in] K=256,
// single fp16 term. LDS per buffer: A section + W section, each 512 granules
// of 16B in [g(4)][r(128)] layout. Waves 0,1 stage A; waves 2,3 stage W.
__global__ __launch_bounds__(256, 4) void gemm_mfma(
    const ushort_t* __restrict__ inh,
    const ushort_t* __restrict__ aggh,
    const ushort_t* __restrict__ wimg,
    const float* __restrict__ bias,
    float* __restrict__ outf, ushort_t* __restrict__ outh,
    int n)
{
    __shared__ ushort_t lds[2][2][4096];   // 32 KB: [buf][A/W][8KB]
    const int tid = threadIdx.x;
    const int l = tid & 63;
    const int w = tid >> 6;
    const int ws = w & 1;
    const int m0 = blockIdx.x * 128;
    const int lr = l & 15, lg = l >> 4;
    const int rbase = (w >> 1) * 64, cbase = (w & 1) * 64;

    f32x4 acc[4][4];
    #pragma unroll
    for (int a = 0; a < 4; ++a)
        #pragma unroll
        for (int b = 0; b < 4; ++b) acc[a][b] = (f32x4){0.f, 0.f, 0.f, 0.f};

    auto stage = [&](int buf, int kc) {
        if (w < 2) {
            const ushort_t* src = (kc < 4) ? aggh : inh;
            const int kcl = (kc & 3) * 32;
            #pragma unroll
            for (int i = 0; i < 4; ++i) {
                int q0 = ws * 256 + i * 64;        // granule base of this call
                int q = q0 + l;
                int g = q >> 7, r = q & 127;
                gld_lds16(src + (size_t)(m0 + r) * DIM + kcl + g * 8,
                          &lds[buf][0][q0 * 8]);
            }
        } else {
            const ushort_t* src = wimg + (size_t)kc * 4096;
            #pragma unroll
            for (int i = 0; i < 4; ++i) {
                int q0 = ws * 256 + i * 64;
                gld_lds16(src + (size_t)(q0 + l) * 8, &lds[buf][1][q0 * 8]);
            }
        }
    };

    stage(0, 0);
    __syncthreads();
    int cur = 0;
    for (int kc = 0; kc < 8; ++kc) {
        if (kc < 7) stage(cur ^ 1, kc + 1);
        f16x8 fa[4], fw[4];
        #pragma unroll
        for (int f = 0; f < 4; ++f) {
            int ar = rbase + f * 16 + lr;
            fa[f] = *reinterpret_cast<const f16x8*>(&lds[cur][0][(lg * 128 + ar) * 8]);
            int cn = cbase + f * 16 + lr;
            fw[f] = *reinterpret_cast<const f16x8*>(&lds[cur][1][(lg * 128 + cn) * 8]);
        }
        #pragma unroll
        for (int fm = 0; fm < 4; ++fm)
            #pragma unroll
            for (int fn = 0; fn < 4; ++fn)
                acc[fm][fn] = __builtin_amdgcn_mfma_f32_16x16x32_f16(fa[fm], fw[fn], acc[fm][fn], 0, 0, 0);
        __syncthreads();
        cur ^= 1;
    }

    #pragma unroll
    for (int fn = 0; fn < 4; ++fn) {
        int col = cbase + fn * 16 + lr;
        float bv = bias[col];
        #pragma unroll
        for (int fm = 0; fm < 4; ++fm) {
            int row0 = m0 + rbase + fm * 16 + lg * 4;
            #pragma unroll
            for (int e = 0; e < 4; ++e) {
                int row = row0 + e;
                if (row < n) {
                    float v = fmaxf(acc[fm][fn][e] + bv, 0.f);
                    size_t o = (size_t)row * DIM + col;
                    if (outf) outf[o] = v;
                    if (outh) outh[o] = f2h(v);
                }
            }
        }
    }
}

// --------------------------------- launch ----------------------------------
extern "C" void kernel_launch(void* const* d_in, const int* in_sizes, int n_in,
                              void* d_out, int out_size, void* d_ws, size_t ws_size,
                              hipStream_t stream) {
    const float* x          = (const float*)d_in[0];
    const int*   edge_index = (const int*)d_in[1];
    const float* edge_attr  = (const float*)d_in[2];
    const float* Wrel1 = (const float*)d_in[3];
    const float* b1    = (const float*)d_in[4];
    const float* Wroot1= (const float*)d_in[5];
    const float* Wrel2 = (const float*)d_in[6];
    const float* b2    = (const float*)d_in[7];
    const float* Wroot2= (const float*)d_in[8];
    const float* Wrel3 = (const float*)d_in[9];
    const float* b3    = (const float*)d_in[10];
    const float* Wroot3= (const float*)d_in[11];

    const int N = in_sizes[0] / DIM;
    const int E = in_sizes[2];
    const size_t ND = (size_t)N * DIM;

    size_t off = 0;
    auto carve = [&](size_t bytes) -> char* {
        char* p = (char*)d_ws + off;
        off = (off + bytes + 255) & ~(size_t)255;
        return p;
    };
    int*   counts  = (int*)  carve((size_t)N * 4);
    int*   total   = (int*)  carve(256);
    size_t zero_end = off;
    int*   begb    = (int*)  carve((size_t)N * 4);
    float* deg_inv = (float*)carve((size_t)N * 4);
    int*   rank    = (int*)  carve((size_t)E * 4);
    int2*  pk      = (int2*) carve((size_t)E * 8);
    ushort_t* w1 = (ushort_t*)carve(65536);
    ushort_t* w2 = (ushort_t*)carve(65536);
    ushort_t* w3 = (ushort_t*)carve(65536);
    ushort_t* g  = (ushort_t*)carve(ND * 2);    // agg fp16
    ushort_t* fx = (ushort_t*)carve(ND * 2);    // x fp16 -> later layer-2 out
    ushort_t* f1 = (ushort_t*)carve(ND * 2);    // layer-1 out
    carve(32768);                               // pad for OOB tile staging reads
    (void)ws_size; (void)n_in; (void)out_size;

    // CSR build
    hipMemsetAsync(counts, 0, zero_end, stream);
    hist_kernel<<<(E + 255) / 256, 256, 0, stream>>>(edge_index + E, counts, rank, E);
    assign_kernel<<<(N + 255) / 256, 256, 0, stream>>>(counts, begb, deg_inv, total, N);
    scatter_kernel<<<(E + 255) / 256, 256, 0, stream>>>(edge_index, edge_attr, begb, rank, pk, E);

    // precision prep
    cvt_kernel<<<(int)((ND / 4 + 255) / 256), 256, 0, stream>>>(x, fx, (int)(ND / 4));
    prep_w_kernel<<<128, 256, 0, stream>>>(Wrel1, Wroot1, w1);
    prep_w_kernel<<<128, 256, 0, stream>>>(Wrel2, Wroot2, w2);
    prep_w_kernel<<<128, 256, 0, stream>>>(Wrel3, Wroot3, w3);

    dim3 aggGrid((N + 3) / 4);
    dim3 gemmGrid((N + 127) / 128);

    // Layer 1: x -> f1
    aggregate_kernel<<<aggGrid, 256, 0, stream>>>(fx, pk, begb, counts, deg_inv, g, N);
    gemm_mfma<<<gemmGrid, 256, 0, stream>>>(fx, g, w1, b1, nullptr, f1, N);
    // Layer 2: f1 -> fx (fx dead after layer-1 gemm)
    aggregate_kernel<<<aggGrid, 256, 0, stream>>>(f1, pk, begb, counts, deg_inv, g, N);
    gemm_mfma<<<gemmGrid, 256, 0, stream>>>(f1, g, w2, b2, nullptr, fx, N);
    // Layer 3: fx -> d_out (f32)
    aggregate_kernel<<<aggGrid, 256, 0, stream>>>(fx, pk, begb, counts, deg_inv, g, N);
    gemm_mfma<<<gemmGrid, 256, 0, stream>>>(fx, g, w3, b3, (float*)d_out, nullptr, N);
}